// Round 19
// baseline (153.587 us; speedup 1.0000x reference)
//
#include <hip/hip_runtime.h>
#include <hip/hip_bf16.h>
#include <math.h>

typedef float f32x4 __attribute__((ext_vector_type(4)));
typedef __bf16 bf16_t;
typedef bf16_t bf16x8 __attribute__((ext_vector_type(8)));
typedef bf16_t bf16x4 __attribute__((ext_vector_type(4)));

__device__ __forceinline__ float act_softplus(float x) {
    return fmaxf(x, 0.f) + log1pf(expf(-fabsf(x)));
}
__device__ __forceinline__ float act_gelu(float x) {
    return 0.5f * x * (1.f + erff(x * 0.70710678118654752f));
}

// async global->LDS, 16B per lane; LDS dest = wave-uniform base + lane*16
__device__ __forceinline__ void gload_lds16(const bf16_t* g, bf16_t* l) {
    __builtin_amdgcn_global_load_lds(
        (const __attribute__((address_space(1))) unsigned int*)g,
        (__attribute__((address_space(3))) unsigned int*)l, 16, 0, 0);
}

template<int N_IMM>
__device__ __forceinline__ void wait_vmcnt() {
    if constexpr (N_IMM == 0) asm volatile("s_waitcnt vmcnt(0)" ::: "memory");
    else if constexpr (N_IMM == 2) asm volatile("s_waitcnt vmcnt(2)" ::: "memory");
    else if constexpr (N_IMM == 6) asm volatile("s_waitcnt vmcnt(6)" ::: "memory");
    else static_assert(N_IMM == 0, "unsupported vmcnt");
}

__device__ __forceinline__ void wait_lgkm0() {
    asm volatile("s_waitcnt lgkmcnt(0)" ::: "memory");
    __builtin_amdgcn_sched_barrier(0);
}

// ---------------- fused fp32 -> bf16 conversion for 3 arrays ----------------
__global__ __launch_bounds__(256) void cvt3(const float* __restrict__ a, bf16_t* __restrict__ ao, int na4,
                                            const float* __restrict__ b, bf16_t* __restrict__ bo, int nb4,
                                            const float* __restrict__ c, bf16_t* __restrict__ co, int nc4) {
    int q = blockIdx.x * 256 + threadIdx.x;   // quad index
    const float* src; bf16_t* dst;
    if (q < na4)            { src = a + (size_t)q * 4;              dst = ao + (size_t)q * 4; }
    else if (q < na4 + nb4) { int r = q - na4; src = b + (size_t)r * 4; dst = bo + (size_t)r * 4; }
    else if (q < na4 + nb4 + nc4) { int r = q - na4 - nb4; src = c + (size_t)r * 4; dst = co + (size_t)r * 4; }
    else return;
    float4 v = *reinterpret_cast<const float4*>(src);
    bf16x4 o;
    o[0] = (bf16_t)v.x; o[1] = (bf16_t)v.y; o[2] = (bf16_t)v.z; o[3] = (bf16_t)v.w;
    *reinterpret_cast<bf16x4*>(dst) = o;
}

// ---------------- GEMM1: m201-template port. 256x128 tile, 8 waves, BK=64 ----------------
// R19 = R18 with chunk-index fix: k-slice ks covers chunks ks*4+lg (was ks*2+lg,
// which double-read chunks 2-3 and skipped 6-7 -> absmax 0.88).
// 2 phases per K-tile; per phase: {12 ds_read | 3 gload_lds of tile t+2 |
// [vmcnt(6) at phase B] | barrier | lgkmcnt(0) | setprio(1) 16 MFMA setprio(0)
// | barrier}. Ring-3 LDS (144KB, 1 block/CU). Counted vmcnt(6)+barrier ==
// tile t+1 landed, t+2's 6 loads stay in flight => pipeline never drains.
// Swizzle involution: LDS slot s of row r holds global chunk s^(r&7);
// chunk c read at slot c^(r&7). Grid 256 blocks (1/CU), bijective XCD map.
// Slab epilogue: activated bf16, 64B-line stores.
__global__ __launch_bounds__(512) void gemm1_8ph(const bf16_t* __restrict__ Ag,
                                                 const bf16_t* __restrict__ Wall,
                                                 const float* __restrict__ biasAll,
                                                 bf16_t* __restrict__ OutAll) {
    constexpr int K = 1024;
    constexpr int NKT = K / 64;                 // 16 K-tiles
    __shared__ __align__(16) bf16_t SA[3][256 * 64];   // 32KB each
    __shared__ __align__(16) bf16_t SB[3][128 * 64];   // 16KB each

    const int tid = threadIdx.x;
    const int lane = tid & 63;
    const int w = tid >> 6;                     // 0..7
    const int wr = w >> 1, wc = w & 1;          // 4m x 2n waves; per-wave 64x64

    // bijective XCD map: xcd c gets A-half (c&1) x W-8-tile-group (c>>1)
    const int c = blockIdx.x & 7;
    const int pp = blockIdx.x >> 3;             // 0..31
    const int mt = (c & 1) * 4 + (pp & 3);      // 0..7
    const int ntG = (c >> 1) * 8 + (pp >> 2);   // 0..31
    const int m0 = mt * 256;
    const int sec = ntG >> 3;                   // 0..3 (q,k,v,g)
    const int n0 = (ntG & 7) * 128;             // col base within section
    const bf16_t* Bg = Wall + (size_t)sec * 1024 * 1024;
    const float* bias = biasAll + sec * 1024;
    bf16_t* Cout = OutAll + (size_t)sec * 2048 * 1024;

    const int l15 = lane & 15, lg = lane >> 4;  // frag row sel / k-group
    const int srw = lane >> 3;                  // 0..7 rows per wave per instr
    const int slot = lane & 7;                  // 16B slot in 128B row

    f32x4 acc[4][4] = {};                       // per-wave 64x64

    // one gload instr = 512 thr x 16B = 64 rows x 128B; wave w covers rows +w*8
    auto stageA2 = [&](bf16_t* Ad, int kt, int part) {  // 2 instrs: 128 A-rows
#pragma unroll
        for (int u = 0; u < 2; ++u) {
            int rbase = part * 128 + u * 64;
            int row = rbase + w * 8 + srw;
            int ch = slot ^ (row & 7);
            gload_lds16(&Ag[(size_t)(m0 + row) * K + kt * 64 + ch * 8],
                        &Ad[(rbase + w * 8) * 64]);
        }
    };
    auto stageB1 = [&](bf16_t* Bd, int kt, int part) {  // 1 instr: 64 B-rows
        int rbase = part * 64;
        int row = rbase + w * 8 + srw;
        int ch = slot ^ (row & 7);
        gload_lds16(&Bg[(size_t)(n0 + row) * K + kt * 64 + ch * 8],
                    &Bd[(rbase + w * 8) * 64]);
    };

    // prologue: tiles 0 -> buf0, 1 -> buf1 (6 loads each)
    stageA2(SA[0], 0, 0); stageB1(SB[0], 0, 0);
    stageA2(SA[0], 0, 1); stageB1(SB[0], 0, 1);
    stageA2(SA[1], 1, 0); stageB1(SB[1], 1, 0);
    stageA2(SA[1], 1, 1); stageB1(SB[1], 1, 1);
    wait_vmcnt<6>();                            // tile 0 landed; tile 1 in flight
    __builtin_amdgcn_s_barrier();
    __builtin_amdgcn_sched_barrier(0);

    int cur = 0;
    for (int t = 0; t < NKT; ++t) {
        const bf16_t* Ac = SA[cur];
        const bf16_t* Bc = SB[cur];
        int nx2 = cur + 2; if (nx2 >= 3) nx2 -= 3;     // (t+2)%3
        bf16_t* Ast = SA[nx2];
        bf16_t* Bst = SB[nx2];
        const bool doStage = (t + 2 < NKT);

#pragma unroll
        for (int nh = 0; nh < 2; ++nh) {        // phase A (nh=0), phase B (nh=1)
            // 12 ds_read: A 4 frags x 2 k-slices, B 2 frags x 2 k-slices
            bf16x8 af[4][2], bfv[2][2];
#pragma unroll
            for (int i = 0; i < 4; ++i) {
                int ar = wr * 64 + i * 16 + l15;
#pragma unroll
                for (int ks = 0; ks < 2; ++ks)
                    af[i][ks] = *(const bf16x8*)(&Ac[ar * 64 + ((ks * 4 + lg) ^ (ar & 7)) * 8]);
            }
#pragma unroll
            for (int jj = 0; jj < 2; ++jj) {
                int br = wc * 64 + (nh * 2 + jj) * 16 + l15;
#pragma unroll
                for (int ks = 0; ks < 2; ++ks)
                    bfv[jj][ks] = *(const bf16x8*)(&Bc[br * 64 + ((ks * 4 + lg) ^ (br & 7)) * 8]);
            }
            // stage 3 gloads of tile t+2 (half per phase)
            if (doStage) {
                stageA2(Ast, t + 2, nh);
                stageB1(Bst, t + 2, nh);
            }
            // counted wait once per K-tile (phase B): tile t+1 landed, t+2's 6 in flight
            if (nh == 1) {
                if (t <= NKT - 3)      wait_vmcnt<6>();
                else if (t == NKT - 2) wait_vmcnt<0>();
                // t == NKT-1: nothing outstanding
            }
            __builtin_amdgcn_s_barrier();
            wait_lgkm0();
            __builtin_amdgcn_s_setprio(1);
#pragma unroll
            for (int i = 0; i < 4; ++i)
#pragma unroll
                for (int jj = 0; jj < 2; ++jj)
#pragma unroll
                    for (int ks = 0; ks < 2; ++ks)
                        acc[i][nh * 2 + jj] = __builtin_amdgcn_mfma_f32_16x16x32_bf16(
                            af[i][ks], bfv[jj][ks], acc[i][nh * 2 + jj], 0, 0, 0);
            __builtin_amdgcn_s_setprio(0);
            __builtin_amdgcn_sched_barrier(0);
            __builtin_amdgcn_s_barrier();
        }
        cur = (cur == 2) ? 0 : cur + 1;
    }

    // epilogue: activation + per-wave 2KB slab (in SA[0], all reads done) ->
    // 64B-line bf16x8 stores, 16 rows x 128B per i-step
    bf16_t* slab = &SA[0][0] + w * 1024;        // 16 rows x 64 cols bf16
    const int colbase = n0 + wc * 64;
#pragma unroll
    for (int i = 0; i < 4; ++i) {
#pragma unroll
        for (int j = 0; j < 4; ++j) {
            int gn = colbase + j * 16 + l15;
            float bv = bias[gn];
#pragma unroll
            for (int r = 0; r < 4; ++r) {
                float v = acc[i][j][r] + bv;
                float a = (sec < 2) ? act_softplus(v) : act_gelu(v);
                slab[(lg * 4 + r) * 64 + j * 16 + l15] = (bf16_t)a;
            }
        }
        int row16 = lane >> 2, seg = (lane & 3) * 8;
        int gr = m0 + wr * 64 + i * 16 + row16;
        bf16x8 v0 = *(const bf16x8*)(&slab[row16 * 64 + seg]);
        bf16x8 v1 = *(const bf16x8*)(&slab[row16 * 64 + 32 + seg]);
        *(bf16x8*)(&Cout[(size_t)gr * 1024 + colbase + seg]) = v0;
        *(bf16x8*)(&Cout[(size_t)gr * 1024 + colbase + 32 + seg]) = v1;
    }
}

// ---------------- GEMM2: R9 proven fp32-dense template (unchanged) ----------------
template<int BM, int BN, int MR, int NR>
__global__ __launch_bounds__(256) void gemm_bt(const bf16_t* __restrict__ A,
                                               const bf16_t* __restrict__ B,
                                               const float* __restrict__ bias,
                                               float* __restrict__ Cout,
                                               int M, int N) {
    constexpr int K = 1024;
    constexpr int TNUM = K / 32;
    constexpr int WCOLS = BN / (NR * 16);
    constexpr int WROWS = BM / (MR * 16);
    static_assert(WROWS * WCOLS == 4, "4 waves");
    constexpr int ASEG = BM / 64, BSEG = BN / 64;
    constexpr int LOADS = ASEG + BSEG;

    __shared__ __align__(16) bf16_t Sa0[BM * 32];
    __shared__ __align__(16) bf16_t Sb0[BN * 32];
    __shared__ __align__(16) bf16_t Sa1[BM * 32];
    __shared__ __align__(16) bf16_t Sb1[BN * 32];
    __shared__ __align__(16) bf16_t Sa2[BM * 32];
    __shared__ __align__(16) bf16_t Sb2[BN * 32];

    const int tid = threadIdx.x;
    const int lane = tid & 63;
    const int w = tid >> 6;
    const int wr = w / WCOLS, wc = w % WCOLS;

    const int NTM = M / BM, NTN = N / BN;
    const int CHM = NTM >> 3;
    const int chunkN = (NTN * CHM) >> 3;
    const int c = blockIdx.x & 7;
    const int pp = blockIdx.x >> 3;
    const int mt = (c % CHM) * 8 + (pp & 7);
    const int nt = (c / CHM) * chunkN + (pp >> 3);
    const int m0 = mt * BM, n0 = nt * BN;

    const int l15 = lane & 15, lg = lane >> 4;
    const int srow = lane >> 2, pos = lane & 3;

    f32x4 acc[MR][NR] = {};

    auto stageTo = [&](bf16_t* Ad, bf16_t* Bd, int k0) {
#pragma unroll
        for (int t = 0; t < ASEG; ++t) {
            int s = w + t * 4;
            int row = s * 16 + srow;
            int ch = pos ^ ((row >> 1) & 3);
            gload_lds16(&A[(size_t)(m0 + row) * K + k0 + ch * 8], &Ad[s * 512]);
        }
#pragma unroll
        for (int t = 0; t < BSEG; ++t) {
            int s = w + t * 4;
            int row = s * 16 + srow;
            int ch = pos ^ ((row >> 1) & 3);
            gload_lds16(&B[(size_t)(n0 + row) * K + k0 + ch * 8], &Bd[s * 512]);
        }
    };

    auto compute = [&](const bf16_t* Ac, const bf16_t* Bc) {
        bf16x8 af[MR], bfr[NR];
#pragma unroll
        for (int i = 0; i < MR; ++i) {
            int ar = wr * MR * 16 + i * 16 + l15;
            af[i] = *(const bf16x8*)(&Ac[ar * 32 + (lg ^ ((ar >> 1) & 3)) * 8]);
        }
#pragma unroll
        for (int j = 0; j < NR; ++j) {
            int br = wc * NR * 16 + j * 16 + l15;
            bfr[j] = *(const bf16x8*)(&Bc[br * 32 + (lg ^ ((br >> 1) & 3)) * 8]);
        }
#pragma unroll
        for (int i = 0; i < MR; ++i)
#pragma unroll
            for (int j = 0; j < NR; ++j)
                acc[i][j] = __builtin_amdgcn_mfma_f32_16x16x32_bf16(af[i], bfr[j], acc[i][j], 0, 0, 0);
    };

    stageTo(Sa0, Sb0, 0);
    stageTo(Sa1, Sb1, 32);

    for (int t = 0; t < TNUM - 2; t += 3) {
        wait_vmcnt<LOADS>();
        __builtin_amdgcn_s_barrier();
        __builtin_amdgcn_sched_barrier(0);
        stageTo(Sa2, Sb2, (t + 2) * 32);
        compute(Sa0, Sb0);
        __builtin_amdgcn_sched_barrier(0);

        wait_vmcnt<LOADS>();
        __builtin_amdgcn_s_barrier();
        __builtin_amdgcn_sched_barrier(0);
        stageTo(Sa0, Sb0, (t + 3) * 32);
        compute(Sa1, Sb1);
        __builtin_amdgcn_sched_barrier(0);

        wait_vmcnt<LOADS>();
        __builtin_amdgcn_s_barrier();
        __builtin_amdgcn_sched_barrier(0);
        stageTo(Sa1, Sb1, (t + 4) * 32);
        compute(Sa2, Sb2);
        __builtin_amdgcn_sched_barrier(0);
    }
    wait_vmcnt<LOADS>();
    __builtin_amdgcn_s_barrier();
    __builtin_amdgcn_sched_barrier(0);
    compute(Sa0, Sb0);
    __builtin_amdgcn_sched_barrier(0);

    wait_vmcnt<0>();
    __builtin_amdgcn_s_barrier();
    __builtin_amdgcn_sched_barrier(0);
    compute(Sa1, Sb1);

#pragma unroll
    for (int i = 0; i < MR; ++i) {
        int gm_base = m0 + wr * MR * 16 + i * 16 + lg * 4;
#pragma unroll
        for (int j = 0; j < NR; ++j) {
            int gn = n0 + wc * NR * 16 + j * 16 + l15;
            float bv = bias[gn];
#pragma unroll
            for (int r = 0; r < 4; ++r) {
                int gm = gm_base + r;
                Cout[(size_t)gm * N + gn] = acc[i][j][r] + bv;
            }
        }
    }
}

// ---------------- A = K^T Q partials per (b,h); q,k pre-activated bf16 dense ----------------
// qkvga layout: section s at s*2048*1024; element [(b*1024+tok)*1024 + h*64 + e]
__global__ __launch_bounds__(256) void attn_A(const bf16_t* __restrict__ qkvga,
                                              float* __restrict__ Apart) {
    const int bh = blockIdx.x;           // 0..31
    const int p = blockIdx.y;            // 0..7
    const int b = bh >> 4, h = bh & 15;
    const int tid = threadIdx.x;
    __shared__ float ks[32][64];
    __shared__ float qs[32][64];
    float acc[4][4] = {};
    const int dg = tid >> 4, eg = tid & 15;
    const int stok = tid >> 3, se0 = (tid & 7) * 8;
    const bf16_t* qf = qkvga;                             // section 0
    const bf16_t* kf = qkvga + (size_t)2048 * 1024;       // section 1

    for (int t0 = p * 128; t0 < p * 128 + 128; t0 += 32) {
        __syncthreads();
        size_t rowb = (size_t)(b * 1024 + t0 + stok) * 1024 + h * 64 + se0;
        bf16x8 qv8 = *(const bf16x8*)(&qf[rowb]);
        bf16x8 kv8 = *(const bf16x8*)(&kf[rowb]);
#pragma unroll
        for (int jj = 0; jj < 8; ++jj) {
            qs[stok][se0 + jj] = (float)qv8[jj];
            ks[stok][se0 + jj] = (float)kv8[jj];
        }
        __syncthreads();
#pragma unroll 8
        for (int tt = 0; tt < 32; ++tt) {
            f32x4 kv = *(const f32x4*)(&ks[tt][dg * 4]);
            f32x4 qv = *(const f32x4*)(&qs[tt][eg * 4]);
#pragma unroll
            for (int i = 0; i < 4; ++i)
#pragma unroll
                for (int j = 0; j < 4; ++j) acc[i][j] += kv[i] * qv[j];
        }
    }
    float* dst = Apart + ((size_t)p * 32 + bh) * 4096;
#pragma unroll
    for (int i = 0; i < 4; ++i)
#pragma unroll
        for (int j = 0; j < 4; ++j)
            dst[(dg * 4 + i) * 64 + eg * 4 + j] = acc[i][j];
}

// ---------------- reduce partials -> A, compute z ----------------
__global__ __launch_bounds__(256) void reduce_A_z(const float* __restrict__ Apart,
                                                  float* __restrict__ A,
                                                  float* __restrict__ z) {
    const int bh = blockIdx.x;
    const int tid = threadIdx.x;
    __shared__ float As[4096];
    for (int i0 = tid * 4; i0 < 4096; i0 += 1024) {
        f32x4 s = {};
#pragma unroll
        for (int p = 0; p < 8; ++p) {
            f32x4 v = *(const f32x4*)(&Apart[((size_t)p * 32 + bh) * 4096 + i0]);
            s += v;
        }
        *(f32x4*)(&As[i0]) = s;
        *(f32x4*)(&A[(size_t)bh * 4096 + i0]) = s;
    }
    __syncthreads();
    if (tid < 64) {
        float s = 0.f;
#pragma unroll 8
        for (int d = 0; d < 64; ++d) s += As[d * 64 + tid];
        z[bh * 64 + tid] = 1.0f / (s * 0.125f + 1024.0f);
    }
}

// ---------------- Y = ((SCALE*V@A + V) * z * g); v,g pre-activated bf16 dense ----------------
__global__ __launch_bounds__(256) void out_Y(const bf16_t* __restrict__ qkvga,
                                             const float* __restrict__ A,
                                             const float* __restrict__ z,
                                             bf16_t* __restrict__ Y) {
    const int bh = blockIdx.x;
    const int b = bh >> 4, h = bh & 15;
    const int chunk = blockIdx.y;        // 0..15 -> 64 tokens
    const int tid = threadIdx.x;
    __shared__ float As[64][64];         // A[d][e]
    __shared__ float vs[32][64];
    __shared__ float zs[64];
    for (int i = tid; i < 4096; i += 256) As[i >> 6][i & 63] = A[(size_t)bh * 4096 + i];
    if (tid < 64) zs[tid] = z[bh * 64 + tid];
    const bf16_t* vf = qkvga + (size_t)2 * 2048 * 1024;   // section 2
    const bf16_t* gf = qkvga + (size_t)3 * 2048 * 1024;   // section 3
    const int e = tid & 63, trow = tid >> 6;
    const int stok = tid >> 3, se0 = (tid & 7) * 8;

    for (int t0 = chunk * 64; t0 < chunk * 64 + 64; t0 += 32) {
        __syncthreads();
        bf16x8 vv8 = *(const bf16x8*)(&vf[(size_t)(b * 1024 + t0 + stok) * 1024 + h * 64 + se0]);
#pragma unroll
        for (int jj = 0; jj < 8; ++jj) vs[stok][se0 + jj] = (float)vv8[jj];
        __syncthreads();
#pragma unroll
        for (int kk = 0; kk < 8; ++kk) {
            int ml = trow * 8 + kk;
            int m = t0 + ml;
            float s = 0.f;
#pragma unroll 8
            for (int d = 0; d < 64; ++d) s += vs[ml][d] * As[d][e];
            float g = (float)gf[(size_t)(b * 1024 + m) * 1024 + h * 64 + e];
            float o = (s * 0.125f + vs[ml][e]) * zs[e] * g;
            Y[((size_t)b * 1024 + h * 64 + (m >> 4)) * 1024 + ((m & 15) << 6) + e] = (bf16_t)o;
        }
    }
}

extern "C" void kernel_launch(void* const* d_in, const int* in_sizes, int n_in,
                              void* d_out, int out_size, void* d_ws, size_t ws_size,
                              hipStream_t stream) {
    const float* x      = (const float*)d_in[0];
    const float* w_qkvg = (const float*)d_in[1];
    const float* b_qkvg = (const float*)d_in[2];
    const float* w_proj = (const float*)d_in[3];
    const float* b_proj = (const float*)d_in[4];

    char* p = (char*)d_ws;
    bf16_t* xb    = (bf16_t*)p; p += (size_t)2048 * 1024 * 2;     // 4MB
    bf16_t* w1b   = (bf16_t*)p; p += (size_t)4096 * 1024 * 2;     // 8MB
    bf16_t* w2b   = (bf16_t*)p; p += (size_t)1024 * 1024 * 2;     // 2MB
    bf16_t* qkvga = (bf16_t*)p; p += (size_t)4 * 2048 * 1024 * 2; // 16MB activated bf16, 4 dense sections
    float*  Apart = (float*)p;  p += (size_t)8 * 32 * 4096 * 4;   // 4MB
    float*  Afull = (float*)p;  p += (size_t)32 * 4096 * 4;
    float*  zbuf  = (float*)p;  p += (size_t)32 * 64 * 4;
    bf16_t* Ybuf  = (bf16_t*)p; p += (size_t)2048 * 1024 * 2;     // 4MB

    // quad counts: x 524288, w_qkvg 1048576, w_proj 262144 -> 7168 blocks
    cvt3<<<7168, 256, 0, stream>>>(x, xb, 524288, w_qkvg, w1b, 1048576, w_proj, w2b, 262144);

    // GEMM1: m201-template 8-phase, 256x128 tiles -> 256 blocks x 512 threads (1/CU)
    gemm1_8ph<<<256, 512, 0, stream>>>(xb, w1b, b_qkvg, qkvga);

    attn_A<<<dim3(32, 8), 256, 0, stream>>>(qkvga, Apart);
    reduce_A_z<<<32, 256, 0, stream>>>(Apart, Afull, zbuf);
    out_Y<<<dim3(32, 16), 256, 0, stream>>>(qkvga, Afull, zbuf, Ybuf);
    // GEMM2: fp32 dense out (proven fast)
    gemm_bt<64, 64, 2, 2><<<512, 256, 0, stream>>>(Ybuf, w2b, b_proj, (float*)d_out, 2048, 1024);
}

// Round 20
// 94.247 us; speedup vs baseline: 1.6296x; 1.6296x over previous
//
#include <hip/hip_runtime.h>
#include <hip/hip_bf16.h>
#include <math.h>

typedef float f32x4 __attribute__((ext_vector_type(4)));
typedef __bf16 bf16_t;
typedef bf16_t bf16x8 __attribute__((ext_vector_type(8)));
typedef bf16_t bf16x4 __attribute__((ext_vector_type(4)));

__device__ __forceinline__ float act_softplus(float x) {
    return fmaxf(x, 0.f) + log1pf(expf(-fabsf(x)));
}
__device__ __forceinline__ float act_gelu(float x) {
    return 0.5f * x * (1.f + erff(x * 0.70710678118654752f));
}

// async global->LDS, 16B per lane; LDS dest = wave-uniform base + lane*16
__device__ __forceinline__ void gload_lds16(const bf16_t* g, bf16_t* l) {
    __builtin_amdgcn_global_load_lds(
        (const __attribute__((address_space(1))) unsigned int*)g,
        (__attribute__((address_space(3))) unsigned int*)l, 16, 0, 0);
}

template<int N_IMM>
__device__ __forceinline__ void wait_vmcnt() {
    if constexpr (N_IMM == 0) asm volatile("s_waitcnt vmcnt(0)" ::: "memory");
    else if constexpr (N_IMM == 2) asm volatile("s_waitcnt vmcnt(2)" ::: "memory");
    else if constexpr (N_IMM == 4) asm volatile("s_waitcnt vmcnt(4)" ::: "memory");
    else static_assert(N_IMM == 0, "unsupported vmcnt");
}

// ---------------- fused fp32 -> bf16 conversion for 3 arrays ----------------
__global__ __launch_bounds__(256) void cvt3(const float* __restrict__ a, bf16_t* __restrict__ ao, int na4,
                                            const float* __restrict__ b, bf16_t* __restrict__ bo, int nb4,
                                            const float* __restrict__ c, bf16_t* __restrict__ co, int nc4) {
    int q = blockIdx.x * 256 + threadIdx.x;   // quad index
    const float* src; bf16_t* dst;
    if (q < na4)            { src = a + (size_t)q * 4;              dst = ao + (size_t)q * 4; }
    else if (q < na4 + nb4) { int r = q - na4; src = b + (size_t)r * 4; dst = bo + (size_t)r * 4; }
    else if (q < na4 + nb4 + nc4) { int r = q - na4 - nb4; src = c + (size_t)r * 4; dst = co + (size_t)r * 4; }
    else return;
    float4 v = *reinterpret_cast<const float4*>(src);
    bf16x4 o;
    o[0] = (bf16_t)v.x; o[1] = (bf16_t)v.y; o[2] = (bf16_t)v.z; o[3] = (bf16_t)v.w;
    *reinterpret_cast<bf16x4*>(dst) = o;
}

// ---------------- merged qkvg GEMM: 4 sections in one 2048-block launch ----------------
// CHAMPION (R10/R16, 94.0-94.5us total; locked after R12/R18/R19 showed the
// deep-pipelined 1-block/CU schedule regresses 3x at this shape):
// static triple-buffer ring, K unrolled x3, counted vmcnt, raw barriers,
// source-preswizzled linear LDS (0 conflicts), bijective XCD chunk swizzle.
// Epilogue: activation at high TLP, per-wave LDS micro-transpose -> 64B-line
// bf16x8 stores.
__global__ __launch_bounds__(256) void gemm_qkvg(const bf16_t* __restrict__ A,
                                                 const bf16_t* __restrict__ Wall,
                                                 const float* __restrict__ biasAll,
                                                 bf16_t* __restrict__ OutAll) {
    constexpr int BM = 64, BN = 64, MR = 2, NR = 2;
    constexpr int K = 1024, M = 2048, N = 1024;
    constexpr int TNUM = K / 32;
    constexpr int LOADS = 2;

    __shared__ __align__(16) bf16_t Sa0[BM * 32];
    __shared__ __align__(16) bf16_t Sb0[BN * 32];
    __shared__ __align__(16) bf16_t Sa1[BM * 32];
    __shared__ __align__(16) bf16_t Sb1[BN * 32];
    __shared__ __align__(16) bf16_t Sa2[BM * 32];
    __shared__ __align__(16) bf16_t Sb2[BN * 32];

    const int sec = blockIdx.x >> 9;            // 0..3 (q,k,v,g)
    const int bid = blockIdx.x & 511;
    const bf16_t* B = Wall + (size_t)sec * 1024 * 1024;
    const float* bias = biasAll + sec * 1024;
    bf16_t* Cout = OutAll + (size_t)sec * 2048 * 1024;

    const int tid = threadIdx.x;
    const int lane = tid & 63;
    const int w = tid >> 6;
    const int wr = w >> 1, wc = w & 1;          // 2x2 waves of 32x32

    // bijective XCD swizzle within the 512-block section (512%8==0 so c==XCD)
    const int NTM = M / BM, NTN = N / BN;       // 32, 16
    const int CHM = NTM >> 3;                   // 4
    const int chunkN = (NTN * CHM) >> 3;        // 8
    const int c = bid & 7;
    const int pp = bid >> 3;
    const int mt = (c % CHM) * 8 + (pp & 7);
    const int nt = (c / CHM) * chunkN + (pp >> 3);
    const int m0 = mt * BM, n0 = nt * BN;

    const int l15 = lane & 15, lg = lane >> 4;
    const int srow = lane >> 2, pos = lane & 3;

    f32x4 acc[MR][NR] = {};

    auto stageTo2 = [&](bf16_t* Ad, bf16_t* Bd, int k0) {
        int row = w * 16 + srow;
        int ch = pos ^ ((row >> 1) & 3);
        gload_lds16(&A[(size_t)(m0 + row) * K + k0 + ch * 8], &Ad[w * 512]);
        gload_lds16(&B[(size_t)(n0 + row) * K + k0 + ch * 8], &Bd[w * 512]);
    };

    auto compute = [&](const bf16_t* Ac, const bf16_t* Bc) {
        bf16x8 af[MR], bfr[NR];
#pragma unroll
        for (int i = 0; i < MR; ++i) {
            int ar = wr * MR * 16 + i * 16 + l15;
            af[i] = *(const bf16x8*)(&Ac[ar * 32 + (lg ^ ((ar >> 1) & 3)) * 8]);
        }
#pragma unroll
        for (int j = 0; j < NR; ++j) {
            int br = wc * NR * 16 + j * 16 + l15;
            bfr[j] = *(const bf16x8*)(&Bc[br * 32 + (lg ^ ((br >> 1) & 3)) * 8]);
        }
#pragma unroll
        for (int i = 0; i < MR; ++i)
#pragma unroll
            for (int j = 0; j < NR; ++j)
                acc[i][j] = __builtin_amdgcn_mfma_f32_16x16x32_bf16(af[i], bfr[j], acc[i][j], 0, 0, 0);
    };

    stageTo2(Sa0, Sb0, 0);
    stageTo2(Sa1, Sb1, 32);

    for (int t = 0; t < TNUM - 2; t += 3) {
        wait_vmcnt<LOADS>();
        __builtin_amdgcn_s_barrier();
        __builtin_amdgcn_sched_barrier(0);
        stageTo2(Sa2, Sb2, (t + 2) * 32);
        compute(Sa0, Sb0);
        __builtin_amdgcn_sched_barrier(0);

        wait_vmcnt<LOADS>();
        __builtin_amdgcn_s_barrier();
        __builtin_amdgcn_sched_barrier(0);
        stageTo2(Sa0, Sb0, (t + 3) * 32);
        compute(Sa1, Sb1);
        __builtin_amdgcn_sched_barrier(0);

        wait_vmcnt<LOADS>();
        __builtin_amdgcn_s_barrier();
        __builtin_amdgcn_sched_barrier(0);
        stageTo2(Sa1, Sb1, (t + 4) * 32);
        compute(Sa2, Sb2);
        __builtin_amdgcn_sched_barrier(0);
    }
    wait_vmcnt<LOADS>();
    __builtin_amdgcn_s_barrier();
    __builtin_amdgcn_sched_barrier(0);
    compute(Sa0, Sb0);
    __builtin_amdgcn_sched_barrier(0);

    wait_vmcnt<0>();
    __builtin_amdgcn_s_barrier();
    __builtin_amdgcn_sched_barrier(0);
    compute(Sa1, Sb1);

    // epilogue: activation + LDS micro-transpose -> 64B-per-row bf16x8 stores.
    bf16_t* slab = &Sb2[w * 512];              // 16 rows x 32 cols bf16
#pragma unroll
    for (int i = 0; i < MR; ++i) {
#pragma unroll
        for (int j = 0; j < NR; ++j) {
            int gn = n0 + wc * 32 + j * 16 + l15;
            float bv = bias[gn];
#pragma unroll
            for (int r = 0; r < 4; ++r) {
                float v = acc[i][j][r] + bv;
                float a = (sec < 2) ? act_softplus(v) : act_gelu(v);
                slab[(lg * 4 + r) * 32 + j * 16 + l15] = (bf16_t)a;
            }
        }
        int row = lane >> 2, c8 = (lane & 3) * 8;
        bf16x8 val = *(const bf16x8*)(&slab[row * 32 + c8]);
        *(bf16x8*)(&Cout[(size_t)(m0 + wr * 32 + i * 16 + row) * N + n0 + wc * 32 + c8]) = val;
    }
}

// ---------------- GEMM2: R9 proven fp32-dense template ----------------
template<int BM, int BN, int MR, int NR>
__global__ __launch_bounds__(256) void gemm_bt(const bf16_t* __restrict__ A,
                                               const bf16_t* __restrict__ B,
                                               const float* __restrict__ bias,
                                               float* __restrict__ Cout,
                                               int M, int N) {
    constexpr int K = 1024;
    constexpr int TNUM = K / 32;
    constexpr int WCOLS = BN / (NR * 16);
    constexpr int WROWS = BM / (MR * 16);
    static_assert(WROWS * WCOLS == 4, "4 waves");
    constexpr int ASEG = BM / 64, BSEG = BN / 64;
    constexpr int LOADS = ASEG + BSEG;

    __shared__ __align__(16) bf16_t Sa0[BM * 32];
    __shared__ __align__(16) bf16_t Sb0[BN * 32];
    __shared__ __align__(16) bf16_t Sa1[BM * 32];
    __shared__ __align__(16) bf16_t Sb1[BN * 32];
    __shared__ __align__(16) bf16_t Sa2[BM * 32];
    __shared__ __align__(16) bf16_t Sb2[BN * 32];

    const int tid = threadIdx.x;
    const int lane = tid & 63;
    const int w = tid >> 6;
    const int wr = w / WCOLS, wc = w % WCOLS;

    const int NTM = M / BM, NTN = N / BN;
    const int CHM = NTM >> 3;
    const int chunkN = (NTN * CHM) >> 3;
    const int c = blockIdx.x & 7;
    const int pp = blockIdx.x >> 3;
    const int mt = (c % CHM) * 8 + (pp & 7);
    const int nt = (c / CHM) * chunkN + (pp >> 3);
    const int m0 = mt * BM, n0 = nt * BN;

    const int l15 = lane & 15, lg = lane >> 4;
    const int srow = lane >> 2, pos = lane & 3;

    f32x4 acc[MR][NR] = {};

    auto stageTo = [&](bf16_t* Ad, bf16_t* Bd, int k0) {
#pragma unroll
        for (int t = 0; t < ASEG; ++t) {
            int s = w + t * 4;
            int row = s * 16 + srow;
            int ch = pos ^ ((row >> 1) & 3);
            gload_lds16(&A[(size_t)(m0 + row) * K + k0 + ch * 8], &Ad[s * 512]);
        }
#pragma unroll
        for (int t = 0; t < BSEG; ++t) {
            int s = w + t * 4;
            int row = s * 16 + srow;
            int ch = pos ^ ((row >> 1) & 3);
            gload_lds16(&B[(size_t)(n0 + row) * K + k0 + ch * 8], &Bd[s * 512]);
        }
    };

    auto compute = [&](const bf16_t* Ac, const bf16_t* Bc) {
        bf16x8 af[MR], bfr[NR];
#pragma unroll
        for (int i = 0; i < MR; ++i) {
            int ar = wr * MR * 16 + i * 16 + l15;
            af[i] = *(const bf16x8*)(&Ac[ar * 32 + (lg ^ ((ar >> 1) & 3)) * 8]);
        }
#pragma unroll
        for (int j = 0; j < NR; ++j) {
            int br = wc * NR * 16 + j * 16 + l15;
            bfr[j] = *(const bf16x8*)(&Bc[br * 32 + (lg ^ ((br >> 1) & 3)) * 8]);
        }
#pragma unroll
        for (int i = 0; i < MR; ++i)
#pragma unroll
            for (int j = 0; j < NR; ++j)
                acc[i][j] = __builtin_amdgcn_mfma_f32_16x16x32_bf16(af[i], bfr[j], acc[i][j], 0, 0, 0);
    };

    stageTo(Sa0, Sb0, 0);
    stageTo(Sa1, Sb1, 32);

    for (int t = 0; t < TNUM - 2; t += 3) {
        wait_vmcnt<LOADS>();
        __builtin_amdgcn_s_barrier();
        __builtin_amdgcn_sched_barrier(0);
        stageTo(Sa2, Sb2, (t + 2) * 32);
        compute(Sa0, Sb0);
        __builtin_amdgcn_sched_barrier(0);

        wait_vmcnt<LOADS>();
        __builtin_amdgcn_s_barrier();
        __builtin_amdgcn_sched_barrier(0);
        stageTo(Sa0, Sb0, (t + 3) * 32);
        compute(Sa1, Sb1);
        __builtin_amdgcn_sched_barrier(0);

        wait_vmcnt<LOADS>();
        __builtin_amdgcn_s_barrier();
        __builtin_amdgcn_sched_barrier(0);
        stageTo(Sa1, Sb1, (t + 4) * 32);
        compute(Sa2, Sb2);
        __builtin_amdgcn_sched_barrier(0);
    }
    wait_vmcnt<LOADS>();
    __builtin_amdgcn_s_barrier();
    __builtin_amdgcn_sched_barrier(0);
    compute(Sa0, Sb0);
    __builtin_amdgcn_sched_barrier(0);

    wait_vmcnt<0>();
    __builtin_amdgcn_s_barrier();
    __builtin_amdgcn_sched_barrier(0);
    compute(Sa1, Sb1);

#pragma unroll
    for (int i = 0; i < MR; ++i) {
        int gm_base = m0 + wr * MR * 16 + i * 16 + lg * 4;
#pragma unroll
        for (int j = 0; j < NR; ++j) {
            int gn = n0 + wc * NR * 16 + j * 16 + l15;
            float bv = bias[gn];
#pragma unroll
            for (int r = 0; r < 4; ++r) {
                int gm = gm_base + r;
                Cout[(size_t)gm * N + gn] = acc[i][j][r] + bv;
            }
        }
    }
}

// ---------------- A = K^T Q partials per (b,h); q,k pre-activated bf16 dense ----------------
// qkvga layout: section s at s*2048*1024; element [(b*1024+tok)*1024 + h*64 + e]
__global__ __launch_bounds__(256) void attn_A(const bf16_t* __restrict__ qkvga,
                                              float* __restrict__ Apart) {
    const int bh = blockIdx.x;           // 0..31
    const int p = blockIdx.y;            // 0..7
    const int b = bh >> 4, h = bh & 15;
    const int tid = threadIdx.x;
    __shared__ float ks[32][64];
    __shared__ float qs[32][64];
    float acc[4][4] = {};
    const int dg = tid >> 4, eg = tid & 15;
    const int stok = tid >> 3, se0 = (tid & 7) * 8;
    const bf16_t* qf = qkvga;                             // section 0
    const bf16_t* kf = qkvga + (size_t)2048 * 1024;       // section 1

    for (int t0 = p * 128; t0 < p * 128 + 128; t0 += 32) {
        __syncthreads();
        size_t rowb = (size_t)(b * 1024 + t0 + stok) * 1024 + h * 64 + se0;
        bf16x8 qv8 = *(const bf16x8*)(&qf[rowb]);
        bf16x8 kv8 = *(const bf16x8*)(&kf[rowb]);
#pragma unroll
        for (int jj = 0; jj < 8; ++jj) {
            qs[stok][se0 + jj] = (float)qv8[jj];
            ks[stok][se0 + jj] = (float)kv8[jj];
        }
        __syncthreads();
#pragma unroll 8
        for (int tt = 0; tt < 32; ++tt) {
            f32x4 kv = *(const f32x4*)(&ks[tt][dg * 4]);
            f32x4 qv = *(const f32x4*)(&qs[tt][eg * 4]);
#pragma unroll
            for (int i = 0; i < 4; ++i)
#pragma unroll
                for (int j = 0; j < 4; ++j) acc[i][j] += kv[i] * qv[j];
        }
    }
    float* dst = Apart + ((size_t)p * 32 + bh) * 4096;
#pragma unroll
    for (int i = 0; i < 4; ++i)
#pragma unroll
        for (int j = 0; j < 4; ++j)
            dst[(dg * 4 + i) * 64 + eg * 4 + j] = acc[i][j];
}

// ---------------- reduce partials -> A, compute z ----------------
__global__ __launch_bounds__(256) void reduce_A_z(const float* __restrict__ Apart,
                                                  float* __restrict__ A,
                                                  float* __restrict__ z) {
    const int bh = blockIdx.x;
    const int tid = threadIdx.x;
    __shared__ float As[4096];
    for (int i0 = tid * 4; i0 < 4096; i0 += 1024) {
        f32x4 s = {};
#pragma unroll
        for (int p = 0; p < 8; ++p) {
            f32x4 v = *(const f32x4*)(&Apart[((size_t)p * 32 + bh) * 4096 + i0]);
            s += v;
        }
        *(f32x4*)(&As[i0]) = s;
        *(f32x4*)(&A[(size_t)bh * 4096 + i0]) = s;
    }
    __syncthreads();
    if (tid < 64) {
        float s = 0.f;
#pragma unroll 8
        for (int d = 0; d < 64; ++d) s += As[d * 64 + tid];
        z[bh * 64 + tid] = 1.0f / (s * 0.125f + 1024.0f);
    }
}

// ---------------- Y = ((SCALE*V@A + V) * z * g); v,g pre-activated bf16 dense ----------------
__global__ __launch_bounds__(256) void out_Y(const bf16_t* __restrict__ qkvga,
                                             const float* __restrict__ A,
                                             const float* __restrict__ z,
                                             bf16_t* __restrict__ Y) {
    const int bh = blockIdx.x;
    const int b = bh >> 4, h = bh & 15;
    const int chunk = blockIdx.y;        // 0..15 -> 64 tokens
    const int tid = threadIdx.x;
    __shared__ float As[64][64];         // A[d][e]
    __shared__ float vs[32][64];
    __shared__ float zs[64];
    for (int i = tid; i < 4096; i += 256) As[i >> 6][i & 63] = A[(size_t)bh * 4096 + i];
    if (tid < 64) zs[tid] = z[bh * 64 + tid];
    const bf16_t* vf = qkvga + (size_t)2 * 2048 * 1024;   // section 2
    const bf16_t* gf = qkvga + (size_t)3 * 2048 * 1024;   // section 3
    const int e = tid & 63, trow = tid >> 6;
    const int stok = tid >> 3, se0 = (tid & 7) * 8;

    for (int t0 = chunk * 64; t0 < chunk * 64 + 64; t0 += 32) {
        __syncthreads();
        bf16x8 vv8 = *(const bf16x8*)(&vf[(size_t)(b * 1024 + t0 + stok) * 1024 + h * 64 + se0]);
#pragma unroll
        for (int jj = 0; jj < 8; ++jj) vs[stok][se0 + jj] = (float)vv8[jj];
        __syncthreads();
#pragma unroll
        for (int kk = 0; kk < 8; ++kk) {
            int ml = trow * 8 + kk;
            int m = t0 + ml;
            float s = 0.f;
#pragma unroll 8
            for (int d = 0; d < 64; ++d) s += vs[ml][d] * As[d][e];
            float g = (float)gf[(size_t)(b * 1024 + m) * 1024 + h * 64 + e];
            float o = (s * 0.125f + vs[ml][e]) * zs[e] * g;
            Y[((size_t)b * 1024 + h * 64 + (m >> 4)) * 1024 + ((m & 15) << 6) + e] = (bf16_t)o;
        }
    }
}

extern "C" void kernel_launch(void* const* d_in, const int* in_sizes, int n_in,
                              void* d_out, int out_size, void* d_ws, size_t ws_size,
                              hipStream_t stream) {
    const float* x      = (const float*)d_in[0];
    const float* w_qkvg = (const float*)d_in[1];
    const float* b_qkvg = (const float*)d_in[2];
    const float* w_proj = (const float*)d_in[3];
    const float* b_proj = (const float*)d_in[4];

    char* p = (char*)d_ws;
    bf16_t* xb    = (bf16_t*)p; p += (size_t)2048 * 1024 * 2;     // 4MB
    bf16_t* w1b   = (bf16_t*)p; p += (size_t)4096 * 1024 * 2;     // 8MB
    bf16_t* w2b   = (bf16_t*)p; p += (size_t)1024 * 1024 * 2;     // 2MB
    bf16_t* qkvga = (bf16_t*)p; p += (size_t)4 * 2048 * 1024 * 2; // 16MB activated bf16, 4 dense sections
    float*  Apart = (float*)p;  p += (size_t)8 * 32 * 4096 * 4;   // 4MB
    float*  Afull = (float*)p;  p += (size_t)32 * 4096 * 4;
    float*  zbuf  = (float*)p;  p += (size_t)32 * 64 * 4;
    bf16_t* Ybuf  = (bf16_t*)p; p += (size_t)2048 * 1024 * 2;     // 4MB

    // quad counts: x 524288, w_qkvg 1048576, w_proj 262144 -> 7168 blocks
    cvt3<<<7168, 256, 0, stream>>>(x, xb, 524288, w_qkvg, w1b, 1048576, w_proj, w2b, 262144);

    // merged qkvg GEMM: 4 sections x 512 blocks = 2048 blocks (~6/CU resident)
    gemm_qkvg<<<2048, 256, 0, stream>>>(xb, w1b, b_qkvg, qkvga);

    attn_A<<<dim3(32, 8), 256, 0, stream>>>(qkvga, Apart);
    reduce_A_z<<<32, 256, 0, stream>>>(Apart, Afull, zbuf);
    out_Y<<<dim3(32, 16), 256, 0, stream>>>(qkvga, Afull, zbuf, Ybuf);
    // GEMM2: fp32 dense out (proven fast)
    gemm_bt<64, 64, 2, 2><<<512, 256, 0, stream>>>(Ybuf, w2b, b_proj, (float*)d_out, 2048, 1024);
}